// Round 4
// baseline (370.782 us; speedup 1.0000x reference)
//
#include <hip/hip_runtime.h>
#include <hip/hip_bf16.h>

#define NN 10000
#define NE 320000
#define D 256
#define D4 64   // float4 per node row

// ---------------- CSR build (once per call; graph is static across layers) ---

__global__ void hist_kernel(const int* __restrict__ dst, int* __restrict__ cnt, int nE) {
    int e = blockIdx.x * blockDim.x + threadIdx.x;
    if (e < nE) atomicAdd(&cnt[dst[e]], 1);
}

// single-block exclusive scan over NN counts -> rowptr[0..NN] (parallel)
__global__ void scan_kernel(const int* __restrict__ cnt, int* __restrict__ rowptr, int n) {
    __shared__ int part[256];
    int t = threadIdx.x;
    int chunk = (n + 255) / 256;
    int b = t * chunk;
    int e = b + chunk; if (e > n) e = n;
    int s = 0;
    for (int i = b; i < e; ++i) s += cnt[i];
    part[t] = s;
    __syncthreads();
    // Hillis-Steele inclusive scan over the 256 partials
    for (int off = 1; off < 256; off <<= 1) {
        int v = (t >= off) ? part[t - off] : 0;
        __syncthreads();
        part[t] += v;
        __syncthreads();
    }
    int acc = part[t] - s;   // exclusive prefix for this thread's chunk
    for (int i = b; i < e; ++i) { rowptr[i] = acc; acc += cnt[i]; }
    if (e == n && b < n) rowptr[n] = acc;   // total == nE
}

// write SOURCE ids (not edge ids) grouped by dst -> fully coalesced reads later
__global__ void scatter_src_kernel(const int* __restrict__ src, const int* __restrict__ dst,
                                   const int* __restrict__ rowptr, int* __restrict__ cnt,
                                   int* __restrict__ esrc, int nE) {
    int e = blockIdx.x * blockDim.x + threadIdx.x;
    if (e < nE) {
        int d = dst[e];
        int pos = rowptr[d] + atomicAdd(&cnt[d], 1);
        esrc[pos] = src[e];
    }
}

// ---------------- layer-0 norm ----------------------------------------------

__global__ void norm_kernel(const float4* __restrict__ h, float* __restrict__ inv, int n) {
    int wid  = (blockIdx.x * blockDim.x + threadIdx.x) >> 6;
    int lane = threadIdx.x & 63;
    if (wid >= n) return;
    float4 v = h[wid * D4 + lane];
    float s = v.x * v.x + v.y * v.y + v.z * v.z + v.w * v.w;
    #pragma unroll
    for (int o = 32; o; o >>= 1) s += __shfl_xor(s, o);
    if (lane == 0) inv[wid] = rsqrtf(s + 1e-16f);
}

// ---------------- fused layer ------------------------------------------------
// 2 nodes per 256-thread block; 2 waves per node (edge list halved).
// Within a wave: 4 groups of 16 lanes; group g handles edges t === g (mod 4).
// UNIFORM control flow: all groups run ceil(m/8) iterations of 2 edges each;
// invalid slots are clamped to edge 0 and predicated out with e = 0.
// Feature layout per edge: lane (g,q) loads float4s {q, 16+q, 32+q, 48+q}.

__device__ __forceinline__ float dot4(float4 a, float4 b) {
    return a.x * b.x + a.y * b.y + a.z * b.z + a.w * b.w;
}

__global__ __launch_bounds__(256, 5)
void fused_kernel(const float4* __restrict__ h, const float* __restrict__ inv,
                  float* __restrict__ invN,
                  const int* __restrict__ rowptr, const int* __restrict__ esrc,
                  const float* __restrict__ betas, int layer,
                  float4* __restrict__ out) {
    __shared__ float4 sC[2][2][64];
    __shared__ float  sD[2][2];

    int tid  = threadIdx.x;
    int wv   = tid >> 6;            // 0..3
    int nib  = wv >> 1;             // node-in-block 0..1
    int half = wv & 1;              // which half of the edge list
    int node = blockIdx.x * 2 + nib;    // grid exact: NN even
    int lane = tid & 63;
    int g = lane >> 4, q = lane & 15;

    const float4* arow = h + node * D4;
    float4 a0 = arow[q], a1 = arow[16 + q], a2 = arow[32 + q], a3 = arow[48 + q];
    float bivd = betas[layer] * inv[node];

    int beg = rowptr[node], end = rowptr[node + 1];
    int deg = end - beg;
    int h0  = (deg + 1) >> 1;
    int wbeg = beg + half * h0;
    int wend = half ? end : (beg + h0);

    float4 c0 = {0,0,0,0}, c1 = {0,0,0,0}, c2 = {0,0,0,0}, c3 = {0,0,0,0};
    float dsum = 0.f;

    for (int base = wbeg; base < wend; base += 64) {
        int idx = base + lane;
        int s_l = 0; float iv_l = 0.f;
        if (idx < wend) { s_l = esrc[idx]; iv_l = inv[s_l]; }
        int m = wend - base; if (m > 64) m = 64;

        int iters = (m + 7) >> 3;          // wave-uniform trip count
        for (int it = 0; it < iters; ++it) {
            int tA = (it << 3) + g;        // group g's first edge this iter
            int tB = tA + 4;               // second edge
            bool vA = tA < m, vB = tB < m;
            int cA = vA ? tA : 0, cB = vB ? tB : 0;

            int   sA = __shfl(s_l, cA);    // uniform exec: all 64 lanes here
            float iA = __shfl(iv_l, cA);
            int   sB = __shfl(s_l, cB);
            float iB = __shfl(iv_l, cB);

            const float4* vrA = h + sA * D4;
            const float4* vrB = h + sB * D4;
            float4 v00 = vrA[q], v01 = vrA[16+q], v02 = vrA[32+q], v03 = vrA[48+q];
            float4 v10 = vrB[q], v11 = vrB[16+q], v12 = vrB[32+q], v13 = vrB[48+q];

            float pA = dot4(a0, v00) + dot4(a1, v01) + dot4(a2, v02) + dot4(a3, v03);
            float pB = dot4(a0, v10) + dot4(a1, v11) + dot4(a2, v12) + dot4(a3, v13);
            #pragma unroll
            for (int o = 1; o <= 8; o <<= 1) {   // 4-step reduce within 16-lane group
                pA += __shfl_xor(pA, o);
                pB += __shfl_xor(pB, o);
            }
            float eA = vA ? __expf(pA * bivd * iA) : 0.f;
            float eB = vB ? __expf(pB * bivd * iB) : 0.f;
            dsum += eA + eB;
            c0.x += eA * v00.x + eB * v10.x; c0.y += eA * v00.y + eB * v10.y;
            c0.z += eA * v00.z + eB * v10.z; c0.w += eA * v00.w + eB * v10.w;
            c1.x += eA * v01.x + eB * v11.x; c1.y += eA * v01.y + eB * v11.y;
            c1.z += eA * v01.z + eB * v11.z; c1.w += eA * v01.w + eB * v11.w;
            c2.x += eA * v02.x + eB * v12.x; c2.y += eA * v02.y + eB * v12.y;
            c2.z += eA * v02.z + eB * v12.z; c2.w += eA * v02.w + eB * v12.w;
            c3.x += eA * v03.x + eB * v13.x; c3.y += eA * v03.y + eB * v13.y;
            c3.z += eA * v03.z + eB * v13.z; c3.w += eA * v03.w + eB * v13.w;
        }
    }

    // combine the 4 groups' partials within the wave (masks 16, 32)
    dsum += __shfl_xor(dsum, 16); dsum += __shfl_xor(dsum, 32);
#define XG(A) \
    A.x += __shfl_xor(A.x, 16); A.y += __shfl_xor(A.y, 16); \
    A.z += __shfl_xor(A.z, 16); A.w += __shfl_xor(A.w, 16); \
    A.x += __shfl_xor(A.x, 32); A.y += __shfl_xor(A.y, 32); \
    A.z += __shfl_xor(A.z, 32); A.w += __shfl_xor(A.w, 32);
    XG(c0) XG(c1) XG(c2) XG(c3)
#undef XG

    // lane (g,q) owns output float4 index g*16+q (= lane); value comes from c_g
    float4 w = (g == 0) ? c0 : (g == 1) ? c1 : (g == 2) ? c2 : c3;
    sC[nib][half][lane] = w;
    if (lane == 0) sD[nib][half] = dsum;
    __syncthreads();

    if (half == 0) {
        float4 f0 = sC[nib][0][lane];
        float4 f1 = sC[nib][1][lane];
        float ds = sD[nib][0] + sD[nib][1];
        float r = 1.f / (ds + 1e-16f);
        float4 w2;
        w2.x = fmaxf((f0.x + f1.x) * r, 0.f);
        w2.y = fmaxf((f0.y + f1.y) * r, 0.f);
        w2.z = fmaxf((f0.z + f1.z) * r, 0.f);
        w2.w = fmaxf((f0.w + f1.w) * r, 0.f);
        out[node * D4 + lane] = w2;
        // fused next-layer inverse norm (row lives in this wave's registers)
        float s = dot4(w2, w2);
        #pragma unroll
        for (int o = 32; o; o >>= 1) s += __shfl_xor(s, o);
        if (lane == 0) invN[node] = rsqrtf(s + 1e-16f);
    }
}

// ---------------- launch -----------------------------------------------------

extern "C" void kernel_launch(void* const* d_in, const int* in_sizes, int n_in,
                              void* d_out, int out_size, void* d_ws, size_t ws_size,
                              hipStream_t stream) {
    const float* feats = (const float*)d_in[0];
    const int*   src   = (const int*)d_in[1];
    const int*   dst   = (const int*)d_in[2];
    const float* betas = (const float*)d_in[3];
    float* out = (float*)d_out;

    float* hA     = (float*)d_ws;              // NN*D floats
    float* hB     = hA + NN * D;               // NN*D floats
    float* inv0   = hB + NN * D;               // NN floats
    float* inv1   = inv0 + NN;                 // NN floats
    int*   rowptr = (int*)(inv1 + NN);         // NN+1 ints
    int*   cnt    = rowptr + (NN + 1);         // NN ints
    int*   esrc   = cnt + NN;                  // NE ints

    // CSR build (graph identical for all 4 layers)
    hipMemsetAsync(cnt, 0, NN * sizeof(int), stream);
    hist_kernel<<<(NE + 255) / 256, 256, 0, stream>>>(dst, cnt, NE);
    scan_kernel<<<1, 256, 0, stream>>>(cnt, rowptr, NN);
    hipMemsetAsync(cnt, 0, NN * sizeof(int), stream);
    scatter_src_kernel<<<(NE + 255) / 256, 256, 0, stream>>>(src, dst, rowptr, cnt, esrc, NE);

    // layer-0 norms
    norm_kernel<<<(NN * 64 + 255) / 256, 256, 0, stream>>>((const float4*)feats, inv0, NN);

    const float* hin = feats;
    float* invCur = inv0;
    float* invNxt = inv1;
    for (int l = 0; l < 4; ++l) {
        float* hout = (l == 3) ? out : ((l & 1) ? hB : hA);
        fused_kernel<<<NN / 2, 256, 0, stream>>>((const float4*)hin, invCur, invNxt,
                                                 rowptr, esrc, betas, l, (float4*)hout);
        hin = hout;
        float* tmp = invCur; invCur = invNxt; invNxt = tmp;
    }
}

// Round 5
// 256.275 us; speedup vs baseline: 1.4468x; 1.4468x over previous
//
#include <hip/hip_runtime.h>
#include <hip/hip_bf16.h>

#define NN 10000
#define NE 320000
#define D 256
#define D4 64   // float4 per node row

// ---------------- CSR build (once per call; graph is static across layers) ---

__global__ void hist_kernel(const int* __restrict__ dst, int* __restrict__ cnt, int nE) {
    int e = blockIdx.x * blockDim.x + threadIdx.x;
    if (e < nE) atomicAdd(&cnt[dst[e]], 1);
}

// single-block exclusive scan over NN counts -> rowptr[0..NN] (parallel)
__global__ void scan_kernel(const int* __restrict__ cnt, int* __restrict__ rowptr, int n) {
    __shared__ int part[256];
    int t = threadIdx.x;
    int chunk = (n + 255) / 256;
    int b = t * chunk;
    int e = b + chunk; if (e > n) e = n;
    int s = 0;
    for (int i = b; i < e; ++i) s += cnt[i];
    part[t] = s;
    __syncthreads();
    // Hillis-Steele inclusive scan over the 256 partials
    for (int off = 1; off < 256; off <<= 1) {
        int v = (t >= off) ? part[t - off] : 0;
        __syncthreads();
        part[t] += v;
        __syncthreads();
    }
    int acc = part[t] - s;   // exclusive prefix for this thread's chunk
    for (int i = b; i < e; ++i) { rowptr[i] = acc; acc += cnt[i]; }
    if (e == n && b < n) rowptr[n] = acc;   // total == nE
}

// write SOURCE ids (not edge ids) grouped by dst -> fully coalesced reads later
__global__ void scatter_src_kernel(const int* __restrict__ src, const int* __restrict__ dst,
                                   const int* __restrict__ rowptr, int* __restrict__ cnt,
                                   int* __restrict__ esrc, int nE) {
    int e = blockIdx.x * blockDim.x + threadIdx.x;
    if (e < nE) {
        int d = dst[e];
        int pos = rowptr[d] + atomicAdd(&cnt[d], 1);
        esrc[pos] = src[e];
    }
}

// ---------------- layer-0 norm ----------------------------------------------

__global__ void norm_kernel(const float4* __restrict__ h, float* __restrict__ inv, int n) {
    int wid  = (blockIdx.x * blockDim.x + threadIdx.x) >> 6;
    int lane = threadIdx.x & 63;
    if (wid >= n) return;
    float4 v = h[wid * D4 + lane];
    float s = v.x * v.x + v.y * v.y + v.z * v.z + v.w * v.w;
    #pragma unroll
    for (int o = 32; o; o >>= 1) s += __shfl_xor(s, o);
    if (lane == 0) inv[wid] = rsqrtf(s + 1e-16f);
}

// ---------------- fused layer ------------------------------------------------
// One wave per dst node (round-2 structure: full 64-lane contiguous row loads,
// zero dummy traffic). 4-way software pipeline: 4 independent 1KB gathers in
// flight, 4 interleaved shuffle-reduce chains. Epilogue computes next-layer
// inverse norm in registers (no separate norm pass).

__device__ __forceinline__ float dot4(float4 a, float4 b) {
    return a.x * b.x + a.y * b.y + a.z * b.z + a.w * b.w;
}

__global__ void fused_kernel(const float4* __restrict__ h, const float* __restrict__ inv,
                             float* __restrict__ invN,
                             const int* __restrict__ rowptr, const int* __restrict__ esrc,
                             const float* __restrict__ betas, int layer,
                             float4* __restrict__ out, int n) {
    int wid  = (blockIdx.x * blockDim.x + threadIdx.x) >> 6;
    int lane = threadIdx.x & 63;
    if (wid >= n) return;

    float4 a    = h[wid * D4 + lane];   // dst row, register-resident
    float  bivd = betas[layer] * inv[wid];
    int beg = rowptr[wid], end = rowptr[wid + 1];

    float4 acc = make_float4(0.f, 0.f, 0.f, 0.f);
    float dsum = 0.f;

    for (int base = beg; base < end; base += 64) {
        int idx = base + lane;
        int s_l = 0; float iv_l = 0.f;
        if (idx < end) { s_l = esrc[idx]; iv_l = inv[s_l]; }   // coalesced list + tiny gather
        int m = end - base; if (m > 64) m = 64;

        int t = 0;
        // 4-way pipelined: 4 independent row gathers + 4 interleaved reduce chains
        for (; t + 3 < m; t += 4) {
            int   s0 = __shfl(s_l, t),     s1 = __shfl(s_l, t + 1);
            int   s2 = __shfl(s_l, t + 2), s3 = __shfl(s_l, t + 3);
            float i0 = __shfl(iv_l, t),    i1 = __shfl(iv_l, t + 1);
            float i2 = __shfl(iv_l, t + 2), i3 = __shfl(iv_l, t + 3);
            float4 v0 = h[s0 * D4 + lane];
            float4 v1 = h[s1 * D4 + lane];
            float4 v2 = h[s2 * D4 + lane];
            float4 v3 = h[s3 * D4 + lane];
            float p0 = dot4(a, v0);
            float p1 = dot4(a, v1);
            float p2 = dot4(a, v2);
            float p3 = dot4(a, v3);
            #pragma unroll
            for (int o = 32; o; o >>= 1) {
                p0 += __shfl_xor(p0, o);
                p1 += __shfl_xor(p1, o);
                p2 += __shfl_xor(p2, o);
                p3 += __shfl_xor(p3, o);
            }
            float e0 = __expf(p0 * bivd * i0);
            float e1 = __expf(p1 * bivd * i1);
            float e2 = __expf(p2 * bivd * i2);
            float e3 = __expf(p3 * bivd * i3);
            dsum += (e0 + e1) + (e2 + e3);
            acc.x += e0 * v0.x + e1 * v1.x + e2 * v2.x + e3 * v3.x;
            acc.y += e0 * v0.y + e1 * v1.y + e2 * v2.y + e3 * v3.y;
            acc.z += e0 * v0.z + e1 * v1.z + e2 * v2.z + e3 * v3.z;
            acc.w += e0 * v0.w + e1 * v1.w + e2 * v2.w + e3 * v3.w;
        }
        for (; t < m; ++t) {
            int   s0 = __shfl(s_l, t);
            float i0 = __shfl(iv_l, t);
            float4 v0 = h[s0 * D4 + lane];
            float p0 = dot4(a, v0);
            #pragma unroll
            for (int o = 32; o; o >>= 1) p0 += __shfl_xor(p0, o);
            float e0 = __expf(p0 * bivd * i0);
            dsum += e0;
            acc.x += e0 * v0.x; acc.y += e0 * v0.y;
            acc.z += e0 * v0.z; acc.w += e0 * v0.w;
        }
    }

    float r = 1.f / (dsum + 1e-16f);
    float4 w2;
    w2.x = fmaxf(acc.x * r, 0.f); w2.y = fmaxf(acc.y * r, 0.f);
    w2.z = fmaxf(acc.z * r, 0.f); w2.w = fmaxf(acc.w * r, 0.f);
    out[wid * D4 + lane] = w2;

    // fused next-layer inverse norm (row lives in registers)
    float s = dot4(w2, w2);
    #pragma unroll
    for (int o = 32; o; o >>= 1) s += __shfl_xor(s, o);
    if (lane == 0) invN[wid] = rsqrtf(s + 1e-16f);
}

// ---------------- launch -----------------------------------------------------

extern "C" void kernel_launch(void* const* d_in, const int* in_sizes, int n_in,
                              void* d_out, int out_size, void* d_ws, size_t ws_size,
                              hipStream_t stream) {
    const float* feats = (const float*)d_in[0];
    const int*   src   = (const int*)d_in[1];
    const int*   dst   = (const int*)d_in[2];
    const float* betas = (const float*)d_in[3];
    float* out = (float*)d_out;

    float* hA     = (float*)d_ws;              // NN*D floats
    float* hB     = hA + NN * D;               // NN*D floats
    float* inv0   = hB + NN * D;               // NN floats
    float* inv1   = inv0 + NN;                 // NN floats
    int*   rowptr = (int*)(inv1 + NN);         // NN+1 ints
    int*   cnt    = rowptr + (NN + 1);         // NN ints
    int*   esrc   = cnt + NN;                  // NE ints

    // CSR build (graph identical for all 4 layers)
    hipMemsetAsync(cnt, 0, NN * sizeof(int), stream);
    hist_kernel<<<(NE + 255) / 256, 256, 0, stream>>>(dst, cnt, NE);
    scan_kernel<<<1, 256, 0, stream>>>(cnt, rowptr, NN);
    hipMemsetAsync(cnt, 0, NN * sizeof(int), stream);
    scatter_src_kernel<<<(NE + 255) / 256, 256, 0, stream>>>(src, dst, rowptr, cnt, esrc, NE);

    // layer-0 norms (layers 1..3 get theirs from the fused epilogue)
    norm_kernel<<<(NN * 64 + 255) / 256, 256, 0, stream>>>((const float4*)feats, inv0, NN);

    const int node_blocks = (NN * 64 + 255) / 256;   // one wave per node

    const float* hin = feats;
    float* invCur = inv0;
    float* invNxt = inv1;
    for (int l = 0; l < 4; ++l) {
        float* hout = (l == 3) ? out : ((l & 1) ? hB : hA);
        fused_kernel<<<node_blocks, 256, 0, stream>>>((const float4*)hin, invCur, invNxt,
                                                      rowptr, esrc, betas, l,
                                                      (float4*)hout, NN);
        hin = hout;
        float* tmp = invCur; invCur = invNxt; invNxt = tmp;
    }
}

// Round 6
// 191.891 us; speedup vs baseline: 1.9323x; 1.3355x over previous
//
#include <hip/hip_runtime.h>
#include <hip/hip_bf16.h>

#define NN 10000
#define NE 320000
#define D 256
#define D4 64          // float4 per node row
#define BH 128         // histogram blocks
#define EPB (NE / BH)  // 2500 edges per block (exact)

// ---------------- DPP wave-64 sum (VALU pipe, no LDS ops) --------------------

template<int CTRL>
__device__ __forceinline__ float dpp_add(float x) {
    int y = __builtin_amdgcn_update_dpp(0, __float_as_int(x), CTRL, 0xF, 0xF, true);
    return x + __int_as_float(y);
}

// returns the wave-wide sum, broadcast (uniform) via readlane 63
__device__ __forceinline__ float wave_red_sum(float x) {
    x = dpp_add<0x111>(x);   // row_shr:1
    x = dpp_add<0x112>(x);   // row_shr:2
    x = dpp_add<0x114>(x);   // row_shr:4
    x = dpp_add<0x118>(x);   // row_shr:8  -> lane 15/31/47/63 hold row sums
    x = dpp_add<0x142>(x);   // row_bcast15
    x = dpp_add<0x143>(x);   // row_bcast31 -> lane 63 holds wave sum
    return __int_as_float(__builtin_amdgcn_readlane(__float_as_int(x), 63));
}

__device__ __forceinline__ float bcast_lane_f(float x, int t) {
    return __int_as_float(__builtin_amdgcn_readlane(__float_as_int(x), t));
}

// ---------------- CSR build: atomic-free (LDS histograms) --------------------

// Pass 1: per-block LDS histogram; LDS atomicAdd returns local rank per edge.
__global__ void hist_rank_kernel(const int* __restrict__ dst,
                                 int* __restrict__ blockhist, int* __restrict__ rank) {
    __shared__ int lh[NN];                       // 40 KB
    for (int i = threadIdx.x; i < NN; i += 256) lh[i] = 0;
    __syncthreads();
    int e0 = blockIdx.x * EPB, e1 = e0 + EPB;
    for (int e = e0 + threadIdx.x; e < e1; e += 256)
        rank[e] = atomicAdd(&lh[dst[e]], 1);     // LDS atomic: fast, conflict-light
    __syncthreads();
    int* bh = blockhist + blockIdx.x * NN;
    for (int i = threadIdx.x; i < NN; i += 256) bh[i] = lh[i];
}

// Pass 2: per-dst exclusive scan over the BH block histograms; emits cnt.
__global__ void colscan_kernel(int* __restrict__ blockhist, int* __restrict__ cnt, int n) {
    int d = blockIdx.x * blockDim.x + threadIdx.x;
    if (d >= n) return;
    int run = 0;
    for (int b = 0; b < BH; ++b) {
        int v = blockhist[b * NN + d];           // coalesced across d
        blockhist[b * NN + d] = run;
        run += v;
    }
    cnt[d] = run;
}

// Pass 3: single-block exclusive scan over NN counts -> rowptr[0..NN]
__global__ void scan_kernel(const int* __restrict__ cnt, int* __restrict__ rowptr, int n) {
    __shared__ int part[256];
    int t = threadIdx.x;
    int chunk = (n + 255) / 256;
    int b = t * chunk;
    int e = b + chunk; if (e > n) e = n;
    int s = 0;
    for (int i = b; i < e; ++i) s += cnt[i];
    part[t] = s;
    __syncthreads();
    for (int off = 1; off < 256; off <<= 1) {
        int v = (t >= off) ? part[t - off] : 0;
        __syncthreads();
        part[t] += v;
        __syncthreads();
    }
    int acc = part[t] - s;
    for (int i = b; i < e; ++i) { rowptr[i] = acc; acc += cnt[i]; }
    if (e == n && b < n) rowptr[n] = acc;
}

// Pass 4: scatter source ids into CSR order — no atomics.
__global__ void scatter2_kernel(const int* __restrict__ src, const int* __restrict__ dst,
                                const int* __restrict__ rank, const int* __restrict__ blockhist,
                                const int* __restrict__ rowptr, int* __restrict__ esrc, int nE) {
    int e = blockIdx.x * blockDim.x + threadIdx.x;
    if (e >= nE) return;
    int b = e / EPB;                             // const divide -> magic mul
    int d = dst[e];
    esrc[rowptr[d] + blockhist[b * NN + d] + rank[e]] = src[e];
}

// ---------------- layer-0 norm ----------------------------------------------

__global__ void norm_kernel(const float4* __restrict__ h, float* __restrict__ inv, int n) {
    int wid  = (blockIdx.x * blockDim.x + threadIdx.x) >> 6;
    int lane = threadIdx.x & 63;
    if (wid >= n) return;
    float4 v = h[wid * D4 + lane];
    float s = wave_red_sum(v.x * v.x + v.y * v.y + v.z * v.z + v.w * v.w);
    if (lane == 0) inv[wid] = rsqrtf(s + 1e-16f);
}

// ---------------- fused layer ------------------------------------------------
// One wave per dst node; full 64-lane contiguous row loads (zero dummy
// traffic); 4-way pipelined gathers; all cross-lane work on the VALU pipe
// (DPP reduce + readlane broadcasts) — the hot loop issues NO ds ops.

__device__ __forceinline__ float dot4(float4 a, float4 b) {
    return a.x * b.x + a.y * b.y + a.z * b.z + a.w * b.w;
}

__global__ void fused_kernel(const float4* __restrict__ h, const float* __restrict__ inv,
                             float* __restrict__ invN,
                             const int* __restrict__ rowptr, const int* __restrict__ esrc,
                             const float* __restrict__ betas, int layer,
                             float4* __restrict__ out, int n) {
    int wid  = (blockIdx.x * blockDim.x + threadIdx.x) >> 6;
    int lane = threadIdx.x & 63;
    if (wid >= n) return;

    float4 a    = h[wid * D4 + lane];   // dst row, register-resident
    float  bivd = betas[layer] * inv[wid];
    int beg = rowptr[wid], end = rowptr[wid + 1];

    float4 acc = make_float4(0.f, 0.f, 0.f, 0.f);
    float dsum = 0.f;

    for (int base = beg; base < end; base += 64) {
        int idx = base + lane;
        int s_l = 0; float iv_l = 0.f;
        if (idx < end) { s_l = esrc[idx]; iv_l = inv[s_l]; }
        int m = end - base; if (m > 64) m = 64;

        int t = 0;
        for (; t + 3 < m; t += 4) {
            int s0 = __builtin_amdgcn_readlane(s_l, t);
            int s1 = __builtin_amdgcn_readlane(s_l, t + 1);
            int s2 = __builtin_amdgcn_readlane(s_l, t + 2);
            int s3 = __builtin_amdgcn_readlane(s_l, t + 3);
            float4 v0 = h[s0 * D4 + lane];
            float4 v1 = h[s1 * D4 + lane];
            float4 v2 = h[s2 * D4 + lane];
            float4 v3 = h[s3 * D4 + lane];
            float i0 = bcast_lane_f(iv_l, t);
            float i1 = bcast_lane_f(iv_l, t + 1);
            float i2 = bcast_lane_f(iv_l, t + 2);
            float i3 = bcast_lane_f(iv_l, t + 3);
            float p0 = wave_red_sum(dot4(a, v0));
            float p1 = wave_red_sum(dot4(a, v1));
            float p2 = wave_red_sum(dot4(a, v2));
            float p3 = wave_red_sum(dot4(a, v3));
            float e0 = __expf(p0 * bivd * i0);
            float e1 = __expf(p1 * bivd * i1);
            float e2 = __expf(p2 * bivd * i2);
            float e3 = __expf(p3 * bivd * i3);
            dsum += (e0 + e1) + (e2 + e3);
            acc.x += e0 * v0.x + e1 * v1.x + e2 * v2.x + e3 * v3.x;
            acc.y += e0 * v0.y + e1 * v1.y + e2 * v2.y + e3 * v3.y;
            acc.z += e0 * v0.z + e1 * v1.z + e2 * v2.z + e3 * v3.z;
            acc.w += e0 * v0.w + e1 * v1.w + e2 * v2.w + e3 * v3.w;
        }
        for (; t < m; ++t) {
            int   s0 = __builtin_amdgcn_readlane(s_l, t);
            float i0 = bcast_lane_f(iv_l, t);
            float4 v0 = h[s0 * D4 + lane];
            float p0 = wave_red_sum(dot4(a, v0));
            float e0 = __expf(p0 * bivd * i0);
            dsum += e0;
            acc.x += e0 * v0.x; acc.y += e0 * v0.y;
            acc.z += e0 * v0.z; acc.w += e0 * v0.w;
        }
    }

    float r = 1.f / (dsum + 1e-16f);
    float4 w2;
    w2.x = fmaxf(acc.x * r, 0.f); w2.y = fmaxf(acc.y * r, 0.f);
    w2.z = fmaxf(acc.z * r, 0.f); w2.w = fmaxf(acc.w * r, 0.f);
    out[wid * D4 + lane] = w2;

    // fused next-layer inverse norm (row lives in registers)
    float s = wave_red_sum(dot4(w2, w2));
    if (lane == 0) invN[wid] = rsqrtf(s + 1e-16f);
}

// ---------------- launch -----------------------------------------------------

extern "C" void kernel_launch(void* const* d_in, const int* in_sizes, int n_in,
                              void* d_out, int out_size, void* d_ws, size_t ws_size,
                              hipStream_t stream) {
    const float* feats = (const float*)d_in[0];
    const int*   src   = (const int*)d_in[1];
    const int*   dst   = (const int*)d_in[2];
    const float* betas = (const float*)d_in[3];
    float* out = (float*)d_out;

    float* hA        = (float*)d_ws;           // NN*D floats
    float* hB        = hA + NN * D;            // NN*D floats
    float* inv0      = hB + NN * D;            // NN floats
    float* inv1      = inv0 + NN;              // NN floats
    int*   rowptr    = (int*)(inv1 + NN);      // NN+1 ints
    int*   cnt       = rowptr + (NN + 1);      // NN ints
    int*   esrc      = cnt + NN;               // NE ints
    int*   rank      = esrc + NE;              // NE ints
    int*   blockhist = rank + NE;              // BH*NN ints (5.12 MB)

    // CSR build — no global atomics, no memsets
    hist_rank_kernel<<<BH, 256, 0, stream>>>(dst, blockhist, rank);
    colscan_kernel<<<(NN + 255) / 256, 256, 0, stream>>>(blockhist, cnt, NN);
    scan_kernel<<<1, 256, 0, stream>>>(cnt, rowptr, NN);
    scatter2_kernel<<<(NE + 255) / 256, 256, 0, stream>>>(src, dst, rank, blockhist,
                                                          rowptr, esrc, NE);

    // layer-0 norms (layers 1..3 get theirs from the fused epilogue)
    norm_kernel<<<(NN * 64 + 255) / 256, 256, 0, stream>>>((const float4*)feats, inv0, NN);

    const int node_blocks = (NN * 64 + 255) / 256;   // one wave per node

    const float* hin = feats;
    float* invCur = inv0;
    float* invNxt = inv1;
    for (int l = 0; l < 4; ++l) {
        float* hout = (l == 3) ? out : ((l & 1) ? hB : hA);
        fused_kernel<<<node_blocks, 256, 0, stream>>>((const float4*)hin, invCur, invNxt,
                                                      rowptr, esrc, betas, l,
                                                      (float4*)hout, NN);
        hin = hout;
        float* tmp = invCur; invCur = invNxt; invNxt = tmp;
    }
}

// Round 7
// 160.274 us; speedup vs baseline: 2.3134x; 1.1973x over previous
//
#include <hip/hip_runtime.h>
#include <hip/hip_bf16.h>
#include <hip/hip_fp16.h>

#define NN 10000
#define NE 320000
#define D 256
#define D4 64          // float4 per node row (f32)
#define DH2 64         // uint2 (4 halves) per node row (fp16)
#define BH 128         // histogram blocks
#define EPB (NE / BH)  // 2500 edges per block (exact)

// ---------------- DPP wave-64 sum (VALU pipe, no LDS ops) --------------------

template<int CTRL>
__device__ __forceinline__ float dpp_add(float x) {
    int y = __builtin_amdgcn_update_dpp(0, __float_as_int(x), CTRL, 0xF, 0xF, true);
    return x + __int_as_float(y);
}

__device__ __forceinline__ float wave_red_sum(float x) {
    x = dpp_add<0x111>(x);   // row_shr:1
    x = dpp_add<0x112>(x);   // row_shr:2
    x = dpp_add<0x114>(x);   // row_shr:4
    x = dpp_add<0x118>(x);   // row_shr:8
    x = dpp_add<0x142>(x);   // row_bcast15
    x = dpp_add<0x143>(x);   // row_bcast31 -> lane 63 holds wave sum
    return __int_as_float(__builtin_amdgcn_readlane(__float_as_int(x), 63));
}

__device__ __forceinline__ float bcast_lane_f(float x, int t) {
    return __int_as_float(__builtin_amdgcn_readlane(__float_as_int(x), t));
}

union H2U { __half2 h; unsigned u; };

__device__ __forceinline__ float4 unpack_h4(uint2 raw) {
    H2U u0, u1; u0.u = raw.x; u1.u = raw.y;
    float2 f01 = __half22float2(u0.h);
    float2 f23 = __half22float2(u1.h);
    return make_float4(f01.x, f01.y, f23.x, f23.y);
}

__device__ __forceinline__ uint2 pack_h4(float4 v) {
    H2U u0, u1;
    u0.h = __floats2half2_rn(v.x, v.y);
    u1.h = __floats2half2_rn(v.z, v.w);
    return make_uint2(u0.u, u1.u);
}

// ---------------- CSR build: atomic-free (LDS histograms) --------------------

__global__ void hist_rank_kernel(const int* __restrict__ dst,
                                 int* __restrict__ blockhist, int* __restrict__ rank) {
    __shared__ int lh[NN];                       // 40 KB
    for (int i = threadIdx.x; i < NN; i += 256) lh[i] = 0;
    __syncthreads();
    int e0 = blockIdx.x * EPB, e1 = e0 + EPB;
    for (int e = e0 + threadIdx.x; e < e1; e += 256)
        rank[e] = atomicAdd(&lh[dst[e]], 1);     // LDS atomic
    __syncthreads();
    int* bh = blockhist + blockIdx.x * NN;
    for (int i = threadIdx.x; i < NN; i += 256) bh[i] = lh[i];
}

__global__ void colscan_kernel(int* __restrict__ blockhist, int* __restrict__ cnt, int n) {
    int d = blockIdx.x * blockDim.x + threadIdx.x;
    if (d >= n) return;
    int run = 0;
    for (int b = 0; b < BH; ++b) {
        int v = blockhist[b * NN + d];           // coalesced across d
        blockhist[b * NN + d] = run;
        run += v;
    }
    cnt[d] = run;
}

__global__ void scan_kernel(const int* __restrict__ cnt, int* __restrict__ rowptr, int n) {
    __shared__ int part[256];
    int t = threadIdx.x;
    int chunk = (n + 255) / 256;
    int b = t * chunk;
    int e = b + chunk; if (e > n) e = n;
    int s = 0;
    for (int i = b; i < e; ++i) s += cnt[i];
    part[t] = s;
    __syncthreads();
    for (int off = 1; off < 256; off <<= 1) {
        int v = (t >= off) ? part[t - off] : 0;
        __syncthreads();
        part[t] += v;
        __syncthreads();
    }
    int acc = part[t] - s;
    for (int i = b; i < e; ++i) { rowptr[i] = acc; acc += cnt[i]; }
    if (e == n && b < n) rowptr[n] = acc;
}

__global__ void scatter2_kernel(const int* __restrict__ src, const int* __restrict__ dst,
                                const int* __restrict__ rank, const int* __restrict__ blockhist,
                                const int* __restrict__ rowptr, int* __restrict__ esrc, int nE) {
    int e = blockIdx.x * blockDim.x + threadIdx.x;
    if (e >= nE) return;
    int b = e / EPB;
    int d = dst[e];
    esrc[rowptr[d] + blockhist[b * NN + d] + rank[e]] = src[e];
}

// ---------------- layer-0 norm + fp16 mirror ---------------------------------

__global__ void norm_kernel(const float4* __restrict__ h, float* __restrict__ inv,
                            uint2* __restrict__ hh, int n) {
    int wid  = (blockIdx.x * blockDim.x + threadIdx.x) >> 6;
    int lane = threadIdx.x & 63;
    if (wid >= n) return;
    float4 v = h[wid * D4 + lane];
    hh[wid * DH2 + lane] = pack_h4(v);           // fp16 mirror for gathers
    float s = wave_red_sum(v.x * v.x + v.y * v.y + v.z * v.z + v.w * v.w);
    if (lane == 0) inv[wid] = rsqrtf(s + 1e-16f);
}

// ---------------- fused layer ------------------------------------------------
// One wave per dst node. Per-edge gathers read the fp16 mirror (512 B/row,
// 8 B/lane); dst row, dots, exp, and accumulation stay in f32. Epilogue
// writes f32 output + fp16 mirror + next-layer inverse norm.

__device__ __forceinline__ float dot4(float4 a, float4 b) {
    return a.x * b.x + a.y * b.y + a.z * b.z + a.w * b.w;
}

__global__ void fused_kernel(const float4* __restrict__ h, const uint2* __restrict__ hhin,
                             const float* __restrict__ inv, float* __restrict__ invN,
                             const int* __restrict__ rowptr, const int* __restrict__ esrc,
                             const float* __restrict__ betas, int layer,
                             float4* __restrict__ out, uint2* __restrict__ hhout,
                             int writeHH, int n) {
    int wid  = (blockIdx.x * blockDim.x + threadIdx.x) >> 6;
    int lane = threadIdx.x & 63;
    if (wid >= n) return;

    float4 a    = h[wid * D4 + lane];   // dst row, f32, register-resident
    float  bivd = betas[layer] * inv[wid];
    int beg = rowptr[wid], end = rowptr[wid + 1];

    float4 acc = make_float4(0.f, 0.f, 0.f, 0.f);
    float dsum = 0.f;

    for (int base = beg; base < end; base += 64) {
        int idx = base + lane;
        int s_l = 0; float iv_l = 0.f;
        if (idx < end) { s_l = esrc[idx]; iv_l = inv[s_l]; }
        int m = end - base; if (m > 64) m = 64;

        int t = 0;
        for (; t + 3 < m; t += 4) {
            int s0 = __builtin_amdgcn_readlane(s_l, t);
            int s1 = __builtin_amdgcn_readlane(s_l, t + 1);
            int s2 = __builtin_amdgcn_readlane(s_l, t + 2);
            int s3 = __builtin_amdgcn_readlane(s_l, t + 3);
            uint2 r0 = hhin[s0 * DH2 + lane];
            uint2 r1 = hhin[s1 * DH2 + lane];
            uint2 r2 = hhin[s2 * DH2 + lane];
            uint2 r3 = hhin[s3 * DH2 + lane];
            float i0 = bcast_lane_f(iv_l, t);
            float i1 = bcast_lane_f(iv_l, t + 1);
            float i2 = bcast_lane_f(iv_l, t + 2);
            float i3 = bcast_lane_f(iv_l, t + 3);
            float4 v0 = unpack_h4(r0);
            float4 v1 = unpack_h4(r1);
            float4 v2 = unpack_h4(r2);
            float4 v3 = unpack_h4(r3);
            float p0 = wave_red_sum(dot4(a, v0));
            float p1 = wave_red_sum(dot4(a, v1));
            float p2 = wave_red_sum(dot4(a, v2));
            float p3 = wave_red_sum(dot4(a, v3));
            float e0 = __expf(p0 * bivd * i0);
            float e1 = __expf(p1 * bivd * i1);
            float e2 = __expf(p2 * bivd * i2);
            float e3 = __expf(p3 * bivd * i3);
            dsum += (e0 + e1) + (e2 + e3);
            acc.x += e0 * v0.x + e1 * v1.x + e2 * v2.x + e3 * v3.x;
            acc.y += e0 * v0.y + e1 * v1.y + e2 * v2.y + e3 * v3.y;
            acc.z += e0 * v0.z + e1 * v1.z + e2 * v2.z + e3 * v3.z;
            acc.w += e0 * v0.w + e1 * v1.w + e2 * v2.w + e3 * v3.w;
        }
        for (; t < m; ++t) {
            int   s0 = __builtin_amdgcn_readlane(s_l, t);
            float i0 = bcast_lane_f(iv_l, t);
            float4 v0 = unpack_h4(hhin[s0 * DH2 + lane]);
            float p0 = wave_red_sum(dot4(a, v0));
            float e0 = __expf(p0 * bivd * i0);
            dsum += e0;
            acc.x += e0 * v0.x; acc.y += e0 * v0.y;
            acc.z += e0 * v0.z; acc.w += e0 * v0.w;
        }
    }

    float r = 1.f / (dsum + 1e-16f);
    float4 w2;
    w2.x = fmaxf(acc.x * r, 0.f); w2.y = fmaxf(acc.y * r, 0.f);
    w2.z = fmaxf(acc.z * r, 0.f); w2.w = fmaxf(acc.w * r, 0.f);
    out[wid * D4 + lane] = w2;
    if (writeHH) hhout[wid * DH2 + lane] = pack_h4(w2);

    // fused next-layer inverse norm (row lives in registers)
    float s = wave_red_sum(dot4(w2, w2));
    if (lane == 0) invN[wid] = rsqrtf(s + 1e-16f);
}

// ---------------- launch -----------------------------------------------------

extern "C" void kernel_launch(void* const* d_in, const int* in_sizes, int n_in,
                              void* d_out, int out_size, void* d_ws, size_t ws_size,
                              hipStream_t stream) {
    const float* feats = (const float*)d_in[0];
    const int*   src   = (const int*)d_in[1];
    const int*   dst   = (const int*)d_in[2];
    const float* betas = (const float*)d_in[3];
    float* out = (float*)d_out;

    float* hA        = (float*)d_ws;           // NN*D floats
    float* hB        = hA + NN * D;            // NN*D floats
    float* inv0      = hB + NN * D;            // NN floats
    float* inv1      = inv0 + NN;              // NN floats
    int*   rowptr    = (int*)(inv1 + NN);      // NN+1 ints
    int*   cnt       = rowptr + (NN + 1);      // NN ints
    int*   esrc      = cnt + NN;               // NE ints
    int*   rank      = esrc + NE;              // NE ints
    int*   blockhist = rank + NE;              // BH*NN ints (5.12 MB)
    uint2* hh0       = (uint2*)(blockhist + BH * NN);  // NN*D halves (5.12 MB)
    uint2* hh1       = hh0 + NN * DH2;                 // NN*D halves (5.12 MB)

    // CSR build — no global atomics, no memsets
    hist_rank_kernel<<<BH, 256, 0, stream>>>(dst, blockhist, rank);
    colscan_kernel<<<(NN + 255) / 256, 256, 0, stream>>>(blockhist, cnt, NN);
    scan_kernel<<<1, 256, 0, stream>>>(cnt, rowptr, NN);
    scatter2_kernel<<<(NE + 255) / 256, 256, 0, stream>>>(src, dst, rank, blockhist,
                                                          rowptr, esrc, NE);

    // layer-0 norms + fp16 mirror
    norm_kernel<<<(NN * 64 + 255) / 256, 256, 0, stream>>>((const float4*)feats, inv0,
                                                           hh0, NN);

    const int node_blocks = (NN * 64 + 255) / 256;   // one wave per node

    const float* hin = feats;
    const uint2* hhin = hh0;
    float* invCur = inv0;
    float* invNxt = inv1;
    for (int l = 0; l < 4; ++l) {
        float* hout  = (l == 3) ? out : ((l & 1) ? hB : hA);
        uint2* hhout = (l & 1) ? hh0 : hh1;
        fused_kernel<<<node_blocks, 256, 0, stream>>>((const float4*)hin, hhin,
                                                      invCur, invNxt, rowptr, esrc,
                                                      betas, l, (float4*)hout, hhout,
                                                      (l < 3) ? 1 : 0, NN);
        hin = hout;
        hhin = hhout;
        float* tmp = invCur; invCur = invNxt; invNxt = tmp;
    }
}

// Round 8
// 157.640 us; speedup vs baseline: 2.3521x; 1.0167x over previous
//
#include <hip/hip_runtime.h>
#include <hip/hip_bf16.h>
#include <hip/hip_fp16.h>

#define NN 10000
#define NE 320000
#define D 256
#define D4 64          // float4 per node row (f32)
#define DH2 64         // uint2 (4 halves) per node row (fp16)
#define BH 128         // histogram blocks
#define EPB (NE / BH)  // 2500 edges per block (exact)

// ---------------- DPP wave-64 sum (VALU pipe, no LDS ops) --------------------

template<int CTRL>
__device__ __forceinline__ float dpp_add(float x) {
    int y = __builtin_amdgcn_update_dpp(0, __float_as_int(x), CTRL, 0xF, 0xF, true);
    return x + __int_as_float(y);
}

__device__ __forceinline__ float wave_red_sum(float x) {
    x = dpp_add<0x111>(x);   // row_shr:1
    x = dpp_add<0x112>(x);   // row_shr:2
    x = dpp_add<0x114>(x);   // row_shr:4
    x = dpp_add<0x118>(x);   // row_shr:8
    x = dpp_add<0x142>(x);   // row_bcast15
    x = dpp_add<0x143>(x);   // row_bcast31 -> lane 63 holds wave sum
    return __int_as_float(__builtin_amdgcn_readlane(__float_as_int(x), 63));
}

__device__ __forceinline__ float bcast_lane_f(float x, int t) {
    return __int_as_float(__builtin_amdgcn_readlane(__float_as_int(x), t));
}

union H2U { __half2 h; unsigned u; };

__device__ __forceinline__ float4 unpack_h4(uint2 raw) {
    H2U u0, u1; u0.u = raw.x; u1.u = raw.y;
    float2 f01 = __half22float2(u0.h);
    float2 f23 = __half22float2(u1.h);
    return make_float4(f01.x, f01.y, f23.x, f23.y);
}

__device__ __forceinline__ uint2 pack_h4(float4 v) {
    H2U u0, u1;
    u0.h = __floats2half2_rn(v.x, v.y);
    u1.h = __floats2half2_rn(v.z, v.w);
    return make_uint2(u0.u, u1.u);
}

// ---------------- CSR build: atomic-free (LDS histograms) --------------------

__global__ void hist_rank_kernel(const int* __restrict__ dst,
                                 int* __restrict__ blockhist, int* __restrict__ rank) {
    __shared__ int lh[NN];                       // 40 KB
    for (int i = threadIdx.x; i < NN; i += 256) lh[i] = 0;
    __syncthreads();
    int e0 = blockIdx.x * EPB, e1 = e0 + EPB;
    for (int e = e0 + threadIdx.x; e < e1; e += 256)
        rank[e] = atomicAdd(&lh[dst[e]], 1);     // LDS atomic
    __syncthreads();
    int* bh = blockhist + blockIdx.x * NN;
    for (int i = threadIdx.x; i < NN; i += 256) bh[i] = lh[i];
}

__global__ void colscan_kernel(int* __restrict__ blockhist, int* __restrict__ cnt, int n) {
    int d = blockIdx.x * blockDim.x + threadIdx.x;
    if (d >= n) return;
    int run = 0;
    for (int b = 0; b < BH; ++b) {
        int v = blockhist[b * NN + d];           // coalesced across d
        blockhist[b * NN + d] = run;
        run += v;
    }
    cnt[d] = run;
}

__global__ void scan_kernel(const int* __restrict__ cnt, int* __restrict__ rowptr, int n) {
    __shared__ int part[256];
    int t = threadIdx.x;
    int chunk = (n + 255) / 256;
    int b = t * chunk;
    int e = b + chunk; if (e > n) e = n;
    int s = 0;
    for (int i = b; i < e; ++i) s += cnt[i];
    part[t] = s;
    __syncthreads();
    for (int off = 1; off < 256; off <<= 1) {
        int v = (t >= off) ? part[t - off] : 0;
        __syncthreads();
        part[t] += v;
        __syncthreads();
    }
    int acc = part[t] - s;
    for (int i = b; i < e; ++i) { rowptr[i] = acc; acc += cnt[i]; }
    if (e == n && b < n) rowptr[n] = acc;
}

__global__ void scatter2_kernel(const int* __restrict__ src, const int* __restrict__ dst,
                                const int* __restrict__ rank, const int* __restrict__ blockhist,
                                const int* __restrict__ rowptr, int* __restrict__ esrc, int nE) {
    int e = blockIdx.x * blockDim.x + threadIdx.x;
    if (e >= nE) return;
    int b = e / EPB;
    int d = dst[e];
    esrc[rowptr[d] + blockhist[b * NN + d] + rank[e]] = src[e];
}

// ---------------- layer-0 norm + fp16 mirror ---------------------------------

__global__ void norm_kernel(const float4* __restrict__ h, float* __restrict__ inv,
                            uint2* __restrict__ hh, int n) {
    int wid  = (blockIdx.x * blockDim.x + threadIdx.x) >> 6;
    int lane = threadIdx.x & 63;
    if (wid >= n) return;
    float4 v = h[wid * D4 + lane];
    hh[wid * DH2 + lane] = pack_h4(v);           // fp16 mirror for gathers
    float s = wave_red_sum(v.x * v.x + v.y * v.y + v.z * v.z + v.w * v.w);
    if (lane == 0) inv[wid] = rsqrtf(s + 1e-16f);
}

// ---------------- fused layer ------------------------------------------------
// One wave per dst node; fp16-mirror gathers (8 B/lane). Explicit one-group-
// ahead software pipeline: unpack current 4 raw rows -> issue next 4 loads ->
// reduce/exp/accumulate. launch_bounds(256,8) pins VGPR<=64 for 8 waves/SIMD:
// 32 independent 512B gathers in flight per SIMD.

__device__ __forceinline__ float dot4(float4 a, float4 b) {
    return a.x * b.x + a.y * b.y + a.z * b.z + a.w * b.w;
}

__global__ __launch_bounds__(256, 8)
void fused_kernel(const float4* __restrict__ h, const uint2* __restrict__ hhin,
                  const float* __restrict__ inv, float* __restrict__ invN,
                  const int* __restrict__ rowptr, const int* __restrict__ esrc,
                  const float* __restrict__ betas, int layer,
                  float4* __restrict__ out, uint2* __restrict__ hhout,
                  int writeHH, int n) {
    int wid  = (blockIdx.x * blockDim.x + threadIdx.x) >> 6;
    int lane = threadIdx.x & 63;
    if (wid >= n) return;

    float4 a    = h[wid * D4 + lane];   // dst row, f32, register-resident
    float  bivd = betas[layer] * inv[wid];
    int beg = rowptr[wid], end = rowptr[wid + 1];

    float4 acc = make_float4(0.f, 0.f, 0.f, 0.f);
    float dsum = 0.f;

    for (int base = beg; base < end; base += 64) {
        int idx = base + lane;
        int s_l = 0; float iv_l = 0.f;
        if (idx < end) { s_l = esrc[idx]; iv_l = inv[s_l]; }
        int m = end - base; if (m > 64) m = 64;

        int nf = m & ~3;                 // full groups of 4
        uint2 b0, b1, b2, b3;
        if (nf > 0) {                    // prologue: load group 0
            int s0 = __builtin_amdgcn_readlane(s_l, 0);
            int s1 = __builtin_amdgcn_readlane(s_l, 1);
            int s2 = __builtin_amdgcn_readlane(s_l, 2);
            int s3 = __builtin_amdgcn_readlane(s_l, 3);
            b0 = hhin[s0 * DH2 + lane];
            b1 = hhin[s1 * DH2 + lane];
            b2 = hhin[s2 * DH2 + lane];
            b3 = hhin[s3 * DH2 + lane];
        }
        for (int g = 0; g < nf; g += 4) {
            // 1) retire raw buffers into f32 regs
            float4 v0 = unpack_h4(b0);
            float4 v1 = unpack_h4(b1);
            float4 v2 = unpack_h4(b2);
            float4 v3 = unpack_h4(b3);
            float i0 = bcast_lane_f(iv_l, g);
            float i1 = bcast_lane_f(iv_l, g + 1);
            float i2 = bcast_lane_f(iv_l, g + 2);
            float i3 = bcast_lane_f(iv_l, g + 3);
            // 2) issue next group's gathers BEFORE the compute chains
            int gn = g + 4;
            if (gn < nf) {
                int s0 = __builtin_amdgcn_readlane(s_l, gn);
                int s1 = __builtin_amdgcn_readlane(s_l, gn + 1);
                int s2 = __builtin_amdgcn_readlane(s_l, gn + 2);
                int s3 = __builtin_amdgcn_readlane(s_l, gn + 3);
                b0 = hhin[s0 * DH2 + lane];
                b1 = hhin[s1 * DH2 + lane];
                b2 = hhin[s2 * DH2 + lane];
                b3 = hhin[s3 * DH2 + lane];
            }
            // 3) 4 independent reduce chains overlap the loads above
            float p0 = wave_red_sum(dot4(a, v0));
            float p1 = wave_red_sum(dot4(a, v1));
            float p2 = wave_red_sum(dot4(a, v2));
            float p3 = wave_red_sum(dot4(a, v3));
            float e0 = __expf(p0 * bivd * i0);
            float e1 = __expf(p1 * bivd * i1);
            float e2 = __expf(p2 * bivd * i2);
            float e3 = __expf(p3 * bivd * i3);
            dsum += (e0 + e1) + (e2 + e3);
            acc.x += e0 * v0.x + e1 * v1.x + e2 * v2.x + e3 * v3.x;
            acc.y += e0 * v0.y + e1 * v1.y + e2 * v2.y + e3 * v3.y;
            acc.z += e0 * v0.z + e1 * v1.z + e2 * v2.z + e3 * v3.z;
            acc.w += e0 * v0.w + e1 * v1.w + e2 * v2.w + e3 * v3.w;
        }
        for (int t = nf; t < m; ++t) {
            int   s0 = __builtin_amdgcn_readlane(s_l, t);
            float i0 = bcast_lane_f(iv_l, t);
            float4 v0 = unpack_h4(hhin[s0 * DH2 + lane]);
            float p0 = wave_red_sum(dot4(a, v0));
            float e0 = __expf(p0 * bivd * i0);
            dsum += e0;
            acc.x += e0 * v0.x; acc.y += e0 * v0.y;
            acc.z += e0 * v0.z; acc.w += e0 * v0.w;
        }
    }

    float r = 1.f / (dsum + 1e-16f);
    float4 w2;
    w2.x = fmaxf(acc.x * r, 0.f); w2.y = fmaxf(acc.y * r, 0.f);
    w2.z = fmaxf(acc.z * r, 0.f); w2.w = fmaxf(acc.w * r, 0.f);
    out[wid * D4 + lane] = w2;
    if (writeHH) hhout[wid * DH2 + lane] = pack_h4(w2);

    // fused next-layer inverse norm (row lives in registers)
    float s = wave_red_sum(dot4(w2, w2));
    if (lane == 0) invN[wid] = rsqrtf(s + 1e-16f);
}

// ---------------- launch -----------------------------------------------------

extern "C" void kernel_launch(void* const* d_in, const int* in_sizes, int n_in,
                              void* d_out, int out_size, void* d_ws, size_t ws_size,
                              hipStream_t stream) {
    const float* feats = (const float*)d_in[0];
    const int*   src   = (const int*)d_in[1];
    const int*   dst   = (const int*)d_in[2];
    const float* betas = (const float*)d_in[3];
    float* out = (float*)d_out;

    float* hA        = (float*)d_ws;           // NN*D floats
    float* hB        = hA + NN * D;            // NN*D floats
    float* inv0      = hB + NN * D;            // NN floats
    float* inv1      = inv0 + NN;              // NN floats
    int*   rowptr    = (int*)(inv1 + NN);      // NN+1 ints
    int*   cnt       = rowptr + (NN + 1);      // NN ints
    int*   esrc      = cnt + NN;               // NE ints
    int*   rank      = esrc + NE;              // NE ints
    int*   blockhist = rank + NE;              // BH*NN ints (5.12 MB)
    uint2* hh0       = (uint2*)(blockhist + BH * NN);  // NN*D halves (5.12 MB)
    uint2* hh1       = hh0 + NN * DH2;                 // NN*D halves (5.12 MB)

    // CSR build — no global atomics, no memsets
    hist_rank_kernel<<<BH, 256, 0, stream>>>(dst, blockhist, rank);
    colscan_kernel<<<(NN + 255) / 256, 256, 0, stream>>>(blockhist, cnt, NN);
    scan_kernel<<<1, 256, 0, stream>>>(cnt, rowptr, NN);
    scatter2_kernel<<<(NE + 255) / 256, 256, 0, stream>>>(src, dst, rank, blockhist,
                                                          rowptr, esrc, NE);

    // layer-0 norms + fp16 mirror
    norm_kernel<<<(NN * 64 + 255) / 256, 256, 0, stream>>>((const float4*)feats, inv0,
                                                           hh0, NN);

    const int node_blocks = (NN * 64 + 255) / 256;   // one wave per node

    const float* hin = feats;
    const uint2* hhin = hh0;
    float* invCur = inv0;
    float* invNxt = inv1;
    for (int l = 0; l < 4; ++l) {
        float* hout  = (l == 3) ? out : ((l & 1) ? hB : hA);
        uint2* hhout = (l & 1) ? hh0 : hh1;
        fused_kernel<<<node_blocks, 256, 0, stream>>>((const float4*)hin, hhin,
                                                      invCur, invNxt, rowptr, esrc,
                                                      betas, l, (float4*)hout, hhout,
                                                      (l < 3) ? 1 : 0, NN);
        hin = hout;
        hhin = hhout;
        float* tmp = invCur; invCur = invNxt; invNxt = tmp;
    }
}

// Round 9
// 157.477 us; speedup vs baseline: 2.3545x; 1.0010x over previous
//
#include <hip/hip_runtime.h>
#include <hip/hip_fp16.h>

#define NN 10000
#define NE 320000
#define D 256
#define BH 128         // histogram blocks
#define EPB (NE / BH)  // 2500 edges per block (exact)

// ---------------- DPP cross-lane helpers (VALU pipe) -------------------------

template<int CTRL>
__device__ __forceinline__ float dpp_add(float x) {
    int y = __builtin_amdgcn_update_dpp(0, __float_as_int(x), CTRL, 0xF, 0xF, true);
    return x + __int_as_float(y);
}

// 32-lane reduce: after this, lane31 = sum(lanes 0..31), lane63 = sum(lanes 32..63)
__device__ __forceinline__ float red32(float x) {
    x = dpp_add<0x111>(x);   // row_shr:1
    x = dpp_add<0x112>(x);   // row_shr:2
    x = dpp_add<0x114>(x);   // row_shr:4
    x = dpp_add<0x118>(x);   // row_shr:8  -> lane 15/31/47/63 hold 16-lane sums
    x = dpp_add<0x142>(x);   // row_bcast15 -> lane31 += lane15, lane63 += lane47
    return x;
}

__device__ __forceinline__ float rl_f(float x, int t) {
    return __int_as_float(__builtin_amdgcn_readlane(__float_as_int(x), t));
}

union H2U { __half2 h; unsigned u; };

__device__ __forceinline__ void unpack8(uint4 r, float* v) {
    H2U a, b, c, d; a.u = r.x; b.u = r.y; c.u = r.z; d.u = r.w;
    float2 f;
    f = __half22float2(a.h); v[0] = f.x; v[1] = f.y;
    f = __half22float2(b.h); v[2] = f.x; v[3] = f.y;
    f = __half22float2(c.h); v[4] = f.x; v[5] = f.y;
    f = __half22float2(d.h); v[6] = f.x; v[7] = f.y;
}

// ---------------- CSR build: atomic-free (LDS histograms) --------------------

__global__ void hist_rank_kernel(const int* __restrict__ dst,
                                 int* __restrict__ blockhist, int* __restrict__ rank) {
    __shared__ int lh[NN];                       // 40 KB
    for (int i = threadIdx.x; i < NN; i += 256) lh[i] = 0;
    __syncthreads();
    int e0 = blockIdx.x * EPB, e1 = e0 + EPB;
    for (int e = e0 + threadIdx.x; e < e1; e += 256)
        rank[e] = atomicAdd(&lh[dst[e]], 1);     // LDS atomic
    __syncthreads();
    int* bh = blockhist + blockIdx.x * NN;
    for (int i = threadIdx.x; i < NN; i += 256) bh[i] = lh[i];
}

__global__ void colscan_kernel(int* __restrict__ blockhist, int* __restrict__ cnt, int n) {
    int d = blockIdx.x * blockDim.x + threadIdx.x;
    if (d >= n) return;
    int run = 0;
    for (int b = 0; b < BH; ++b) {
        int v = blockhist[b * NN + d];           // coalesced across d
        blockhist[b * NN + d] = run;
        run += v;
    }
    cnt[d] = run;
}

__global__ void scan_kernel(const int* __restrict__ cnt, int* __restrict__ rowptr, int n) {
    __shared__ int part[256];
    int t = threadIdx.x;
    int chunk = (n + 255) / 256;
    int b = t * chunk;
    int e = b + chunk; if (e > n) e = n;
    int s = 0;
    for (int i = b; i < e; ++i) s += cnt[i];
    part[t] = s;
    __syncthreads();
    for (int off = 1; off < 256; off <<= 1) {
        int v = (t >= off) ? part[t - off] : 0;
        __syncthreads();
        part[t] += v;
        __syncthreads();
    }
    int acc = part[t] - s;
    for (int i = b; i < e; ++i) { rowptr[i] = acc; acc += cnt[i]; }
    if (e == n && b < n) rowptr[n] = acc;
}

__global__ void scatter2_kernel(const int* __restrict__ src, const int* __restrict__ dst,
                                const int* __restrict__ rank, const int* __restrict__ blockhist,
                                const int* __restrict__ rowptr, int* __restrict__ esrc, int nE) {
    int e = blockIdx.x * blockDim.x + threadIdx.x;
    if (e >= nE) return;
    int b = e / EPB;
    int d = dst[e];
    esrc[rowptr[d] + blockhist[b * NN + d] + rank[e]] = src[e];
}

// ---------------- layer-0: normalized fp16 mirror + norms --------------------

__global__ void norm_kernel(const float4* __restrict__ h, uint2* __restrict__ hn,
                            float* __restrict__ nrm, int n) {
    int wid  = (blockIdx.x * blockDim.x + threadIdx.x) >> 6;
    int lane = threadIdx.x & 63;
    if (wid >= n) return;
    float4 v = h[wid * 64 + lane];
    float s = red32(v.x * v.x + v.y * v.y + v.z * v.z + v.w * v.w);
    float tot = rl_f(s, 31) + rl_f(s, 63);
    float rs = rsqrtf(tot + 1e-16f);
    H2U u0, u1;
    u0.h = __floats2half2_rn(v.x * rs, v.y * rs);
    u1.h = __floats2half2_rn(v.z * rs, v.w * rs);
    hn[wid * 64 + lane] = make_uint2(u0.u, u1.u);   // normalized fp16 row
    if (lane == 0) nrm[wid] = 1.0f / rs;            // ||h|| (for aggregation weight)
}

// ---------------- fused layer ------------------------------------------------
// One wave per dst node. fp16 NORMALIZED mirror rows are 512 B = 32 lanes x
// 16 B, so ONE dwordx4 wave-load fetches TWO edge rows (lanes 0-31 -> edge A,
// lanes 32-63 -> edge B): half the memory requests per edge. Dot = cos
// directly (both sides normalized); aggregation weight = ex * ||h_src||.
// Denominator uses plain ex. Per-lane 8-float accumulators; halves combined
// once per node via shfl_xor(32).

__global__ __launch_bounds__(256, 6)
void fused_kernel(const uint4* __restrict__ hnin, const float* __restrict__ nrmin,
                  const int* __restrict__ rowptr, const int* __restrict__ esrc,
                  const float* __restrict__ betas, int layer,
                  float4* __restrict__ outf, uint4* __restrict__ hnout,
                  float* __restrict__ nrmout, int lastLayer, int n) {
    int wid  = (blockIdx.x * blockDim.x + threadIdx.x) >> 6;
    int lane = threadIdx.x & 63;
    if (wid >= n) return;
    int q = lane & 31;
    bool hiHalf = lane >= 32;

    float a[8];
    unpack8(hnin[wid * 32 + q], a);      // dst row (normalized), both halves same
    float beta = betas[layer];

    int beg = rowptr[wid], end = rowptr[wid + 1];
    float acc[8] = {0, 0, 0, 0, 0, 0, 0, 0};
    float dsum = 0.f;

    for (int base = beg; base < end; base += 64) {
        int idx = base + lane;
        int s_l = 0; float nm_l = 0.f;
        if (idx < end) { s_l = esrc[idx]; nm_l = nrmin[s_l]; }
        int m = end - base; if (m > 64) m = 64;

        int nf = m & ~3;                 // full groups of 4 edges (2 loads)
        uint4 b0, b1;
        if (nf > 0) {
            int sA = __builtin_amdgcn_readlane(s_l, 0);
            int sB = __builtin_amdgcn_readlane(s_l, 1);
            int sC = __builtin_amdgcn_readlane(s_l, 2);
            int sD = __builtin_amdgcn_readlane(s_l, 3);
            b0 = hnin[(hiHalf ? sB : sA) * 32 + q];
            b1 = hnin[(hiHalf ? sD : sC) * 32 + q];
        }
        for (int g = 0; g < nf; g += 4) {
            float v0[8], v1[8];
            unpack8(b0, v0);
            unpack8(b1, v1);
            float nmA = rl_f(nm_l, g),     nmB = rl_f(nm_l, g + 1);
            float nmC = rl_f(nm_l, g + 2), nmD = rl_f(nm_l, g + 3);
            int gn = g + 4;
            if (gn < nf) {               // issue next 2 two-row gathers early
                int sA = __builtin_amdgcn_readlane(s_l, gn);
                int sB = __builtin_amdgcn_readlane(s_l, gn + 1);
                int sC = __builtin_amdgcn_readlane(s_l, gn + 2);
                int sD = __builtin_amdgcn_readlane(s_l, gn + 3);
                b0 = hnin[(hiHalf ? sB : sA) * 32 + q];
                b1 = hnin[(hiHalf ? sD : sC) * 32 + q];
            }
            float p0 = 0.f, p1 = 0.f;
            #pragma unroll
            for (int j = 0; j < 8; ++j) { p0 += a[j] * v0[j]; p1 += a[j] * v1[j]; }
            p0 = red32(p0); p1 = red32(p1);
            float xA = __expf(beta * rl_f(p0, 31));
            float xB = __expf(beta * rl_f(p0, 63));
            float xC = __expf(beta * rl_f(p1, 31));
            float xD = __expf(beta * rl_f(p1, 63));
            dsum += (xA + xB) + (xC + xD);            // uniform on all lanes
            float e0 = hiHalf ? xB * nmB : xA * nmA;  // this lane's v0-edge weight
            float e1 = hiHalf ? xD * nmD : xC * nmC;  // this lane's v1-edge weight
            #pragma unroll
            for (int j = 0; j < 8; ++j) acc[j] += e0 * v0[j] + e1 * v1[j];
        }
        for (int t = nf; t < m; ++t) {   // remainder: one edge, both halves same row
            int   sA  = __builtin_amdgcn_readlane(s_l, t);
            float nmA = rl_f(nm_l, t);
            float v0[8]; unpack8(hnin[sA * 32 + q], v0);
            float p0 = 0.f;
            #pragma unroll
            for (int j = 0; j < 8; ++j) p0 += a[j] * v0[j];
            p0 = red32(p0);
            float xA = __expf(beta * rl_f(p0, 31));
            dsum += xA;
            float e0 = hiHalf ? 0.f : xA * nmA;       // count once (low half only)
            #pragma unroll
            for (int j = 0; j < 8; ++j) acc[j] += e0 * v0[j];
        }
    }

    // combine the two half-accumulators (symmetric: all lanes get the sum)
    #pragma unroll
    for (int j = 0; j < 8; ++j) acc[j] += __shfl_xor(acc[j], 32);

    float r = 1.f / (dsum + 1e-16f);
    float w[8];
    float ss = 0.f;
    #pragma unroll
    for (int j = 0; j < 8; ++j) {
        w[j] = fmaxf(acc[j] * r, 0.f);
        ss += w[j] * w[j];
    }
    ss = red32(ss);
    float ssum = rl_f(ss, 31);
    float rs = rsqrtf(ssum + 1e-16f);

    if (!hiHalf) {
        if (lastLayer) {
            outf[wid * 64 + q * 2]     = make_float4(w[0], w[1], w[2], w[3]);
            outf[wid * 64 + q * 2 + 1] = make_float4(w[4], w[5], w[6], w[7]);
        } else {
            H2U u0, u1, u2, u3;
            u0.h = __floats2half2_rn(w[0] * rs, w[1] * rs);
            u1.h = __floats2half2_rn(w[2] * rs, w[3] * rs);
            u2.h = __floats2half2_rn(w[4] * rs, w[5] * rs);
            u3.h = __floats2half2_rn(w[6] * rs, w[7] * rs);
            hnout[wid * 32 + q] = make_uint4(u0.u, u1.u, u2.u, u3.u);
            if (lane == 0) nrmout[wid] = 1.0f / rs;
        }
    }
}

// ---------------- launch -----------------------------------------------------

extern "C" void kernel_launch(void* const* d_in, const int* in_sizes, int n_in,
                              void* d_out, int out_size, void* d_ws, size_t ws_size,
                              hipStream_t stream) {
    const float* feats = (const float*)d_in[0];
    const int*   src   = (const int*)d_in[1];
    const int*   dst   = (const int*)d_in[2];
    const float* betas = (const float*)d_in[3];
    float* out = (float*)d_out;

    uint4* hn0       = (uint4*)d_ws;                   // NN*32 uint4 (5.12 MB)
    uint4* hn1       = hn0 + NN * 32;                  // NN*32 uint4 (5.12 MB)
    float* nrm0      = (float*)(hn1 + NN * 32);        // NN floats
    float* nrm1      = nrm0 + NN;                      // NN floats
    int*   rowptr    = (int*)(nrm1 + NN);              // NN+1 ints
    int*   cnt       = rowptr + (NN + 1);              // NN ints
    int*   esrc      = cnt + NN;                       // NE ints
    int*   rank      = esrc + NE;                      // NE ints
    int*   blockhist = rank + NE;                      // BH*NN ints (5.12 MB)

    // CSR build — no global atomics, no memsets
    hist_rank_kernel<<<BH, 256, 0, stream>>>(dst, blockhist, rank);
    colscan_kernel<<<(NN + 255) / 256, 256, 0, stream>>>(blockhist, cnt, NN);
    scan_kernel<<<1, 256, 0, stream>>>(cnt, rowptr, NN);
    scatter2_kernel<<<(NE + 255) / 256, 256, 0, stream>>>(src, dst, rank, blockhist,
                                                          rowptr, esrc, NE);

    // layer-0: normalized fp16 mirror + norms
    norm_kernel<<<(NN * 64 + 255) / 256, 256, 0, stream>>>((const float4*)feats,
                                                           (uint2*)hn0, nrm0, NN);

    const int node_blocks = (NN + 3) / 4;   // one wave per node, 4 waves/block

    const uint4* hnin = hn0;
    const float* nrmin = nrm0;
    for (int l = 0; l < 4; ++l) {
        uint4* hnout  = (l & 1) ? hn0 : hn1;
        float* nrmout = (l & 1) ? nrm0 : nrm1;
        fused_kernel<<<node_blocks, 256, 0, stream>>>(hnin, nrmin, rowptr, esrc,
                                                      betas, l, (float4*)out,
                                                      hnout, nrmout,
                                                      (l == 3) ? 1 : 0, NN);
        hnin = hnout;
        nrmin = nrmout;
    }
}